// Round 2
// baseline (424.070 us; speedup 1.0000x reference)
//
#include <hip/hip_runtime.h>
#include <cstdint>

// Problem constants (match reference setup_inputs()).
static constexpr int NV = 2000000;   // variables
static constexpr int NC = 2000000;   // clauses

// ws layout:
//   [0, 8,000,000)          uint32 counts[NC]
//   [8,000,000, 10,000,000) uint8  xb[NV]
//   [10,000,000, +4)        int32  running min
static constexpr size_t WS_COUNTS = 0;
static constexpr size_t WS_XB     = 8000000;
static constexpr size_t WS_MIN    = 10000000;

__global__ __launch_bounds__(256) void init_k(uint32_t* __restrict__ counts,
                                              uint8_t* __restrict__ xb,
                                              const float* __restrict__ xv,
                                              int* __restrict__ minslot) {
    int stride = gridDim.x * blockDim.x;
    int i0 = blockIdx.x * blockDim.x + threadIdx.x;
    for (int i = i0; i < NC; i += stride) counts[i] = 0u;
    // xb = floor(xv / 0.50001f) -> 0 or 1 (xv in [0,1)).
    // Keep true IEEE f32 division to match the reference exactly.
    for (int i = i0; i < NV; i += stride)
        xb[i] = (uint8_t)(int)floorf(xv[i] / 0.50001f);
    if (i0 == 0) *minslot = 0x7fffffff;
}

// POS=1: literal value = xb  (count when xb==1)
// POS=0: literal value = 1-xb (count when xb==0)
template<int POS>
__global__ __launch_bounds__(256) void edge_k(const int* __restrict__ adj,
                                              const uint8_t* __restrict__ xb,
                                              uint32_t* __restrict__ counts,
                                              int ne) {
    int stride = gridDim.x * blockDim.x;
    int i0 = blockIdx.x * blockDim.x + threadIdx.x;
    for (int e = i0; e < ne; e += stride) {
        int c = adj[e];        // clause id   (row 0)
        int v = adj[ne + e];   // variable id (row 1)
        int b = (int)xb[v];
        bool sat = POS ? (b != 0) : (b == 0);
        if (sat) atomicAdd(&counts[c], 1u);
    }
}

__global__ __launch_bounds__(256) void min_k(const uint32_t* __restrict__ counts,
                                             int* __restrict__ minslot) {
    int stride = gridDim.x * blockDim.x;
    int i0 = blockIdx.x * blockDim.x + threadIdx.x;
    int lo = 0x7fffffff;
    for (int i = i0; i < NC; i += stride) lo = min(lo, (int)counts[i]);
    // wave-64 butterfly min
    for (int off = 32; off > 0; off >>= 1) lo = min(lo, __shfl_down(lo, off));
    if ((threadIdx.x & 63) == 0) atomicMin(minslot, lo);
}

__global__ void fin_k(const int* __restrict__ minslot, float* __restrict__ out) {
    out[0] = (float)(*minslot);
}

extern "C" void kernel_launch(void* const* d_in, const int* in_sizes, int n_in,
                              void* d_out, int out_size, void* d_ws, size_t ws_size,
                              hipStream_t stream) {
    const float* xv      = (const float*)d_in[0];
    const int* adj_pos   = (const int*)d_in[1];   // int32 per harness contract
    const int* adj_neg   = (const int*)d_in[2];
    // d_in[3] = batch_size (unused)
    float* out = (float*)d_out;

    const int ne = in_sizes[1] / 2;   // edges per polarity (rows: [clause, var])

    char* ws = (char*)d_ws;
    uint32_t* counts = (uint32_t*)(ws + WS_COUNTS);
    uint8_t*  xb     = (uint8_t*) (ws + WS_XB);
    int*      mins   = (int*)     (ws + WS_MIN);

    dim3 blk(256);
    init_k<<<2048, blk, 0, stream>>>(counts, xb, xv, mins);
    edge_k<1><<<2048, blk, 0, stream>>>(adj_pos, xb, counts, ne);
    edge_k<0><<<2048, blk, 0, stream>>>(adj_neg, xb, counts, ne);
    min_k<<<2048, blk, 0, stream>>>(counts, mins);
    fin_k<<<1, 1, 0, stream>>>(mins, out);
}

// Round 3
// 243.778 us; speedup vs baseline: 1.7396x; 1.7396x over previous
//
#include <hip/hip_runtime.h>
#include <cstdint>

// Problem constants (match reference setup_inputs()).
static constexpr int NV = 2000000;   // variables
static constexpr int NC = 2000000;   // clauses

// ---- binned-histogram (multisplit) parameters ----
static constexpr int BIN_SHIFT = 13;                 // 8192 clauses per bin
static constexpr int BIN_RANGE = 1 << BIN_SHIFT;
static constexpr int NB        = (NC + BIN_RANGE - 1) / BIN_RANGE;  // 245
static constexpr int BLOCKS_A  = 1024;               // pass-A blocks (region rows)
static constexpr int CAP       = 64;                 // entries per (block,bin) cell; mean ~32
static constexpr int SPILLCAP  = 131072;

// ws layout (bytes)
static constexpr size_t WS_REG   = 0;                                        // u16 regions
static constexpr size_t REG_BY   = (size_t)BLOCKS_A * NB * CAP * 2;          // 32,112,640
static constexpr size_t WS_CNT   = WS_REG + REG_BY;                          // u32 cnt[NB][BLOCKS_A]
static constexpr size_t CNT_BY   = (size_t)NB * BLOCKS_A * 4;                //  1,003,520
static constexpr size_t WS_XB    = WS_CNT + CNT_BY;                          // u8 xb[NV]
static constexpr size_t WS_SPILL = WS_XB + NV;                               // u32 spill[SPILLCAP]
static constexpr size_t WS_CTRL  = WS_SPILL + (size_t)SPILLCAP * 4;          // spillCur, minslot
static constexpr size_t WS_NEED  = WS_CTRL + 64;

__global__ __launch_bounds__(256) void init_k(const float* __restrict__ xv,
                                              uint8_t* __restrict__ xb,
                                              int* __restrict__ spillCur,
                                              int* __restrict__ minslot,
                                              int nv) {
    int stride = gridDim.x * blockDim.x;
    // xb = floor(xv / 0.50001f) -> 0 or 1; keep true f32 division to match reference.
    for (int i = blockIdx.x * blockDim.x + threadIdx.x; i < nv; i += stride)
        xb[i] = (uint8_t)(int)floorf(xv[i] / 0.50001f);
    if (blockIdx.x == 0 && threadIdx.x == 0) { *spillCur = 0; *minslot = 0x7fffffff; }
}

// Pass A: partition satisfied-edge clause ids into per-(block,bin) regions.
// No per-edge global atomics: slots come from LDS counters; stores are dense
// per-region so L2 write-combines them into full lines.
__global__ __launch_bounds__(256) void passA_k(const int* __restrict__ adj_pos,
                                               const int* __restrict__ adj_neg,
                                               const uint8_t* __restrict__ xb,
                                               uint16_t* __restrict__ regions,
                                               uint32_t* __restrict__ cnt,
                                               uint32_t* __restrict__ spill,
                                               int* __restrict__ spillCur,
                                               int ne, int per_block) {
    __shared__ uint32_t lc[NB];
    for (int i = threadIdx.x; i < NB; i += 256) lc[i] = 0;
    __syncthreads();

    int start = blockIdx.x * per_block;
    int total = 2 * ne;
    int end = min(start + per_block, total);
    for (int e = start + threadIdx.x; e < end; e += 256) {
        int neg = (e >= ne) ? 1 : 0;
        int idx = neg ? (e - ne) : e;
        const int* adj = neg ? adj_neg : adj_pos;
        int c = adj[idx];        // clause id (row 0)
        int v = adj[ne + idx];   // var id    (row 1)
        int b = (int)xb[v];
        if ((b != 0) != (neg != 0)) {   // satisfied literal
            int bin = c >> BIN_SHIFT;
            uint32_t pos = atomicAdd(&lc[bin], 1u);
            if (pos < (uint32_t)CAP) {
                regions[(((size_t)blockIdx.x * NB + bin) << 6) + pos] =
                    (uint16_t)(c & (BIN_RANGE - 1));
            } else {
                int g = atomicAdd(spillCur, 1);
                if (g < SPILLCAP) spill[g] = (uint32_t)c;
            }
        }
    }
    __syncthreads();
    for (int i = threadIdx.x; i < NB; i += 256)
        cnt[(size_t)i * BLOCKS_A + blockIdx.x] = lc[i];
}

// Pass B: one block per bin. LDS histogram over the bin's 8192 clauses,
// then min-reduce and one atomicMin per wave.
__global__ __launch_bounds__(256) void passB_k(const uint16_t* __restrict__ regions,
                                               const uint32_t* __restrict__ cnt,
                                               const uint32_t* __restrict__ spill,
                                               const int* __restrict__ spillCur,
                                               int* __restrict__ minslot,
                                               int nc) {
    __shared__ uint32_t hist[BIN_RANGE];
    __shared__ uint32_t ln[BLOCKS_A];
    int b = blockIdx.x;
    for (int i = threadIdx.x; i < BIN_RANGE; i += 256) hist[i] = 0;
    for (int i = threadIdx.x; i < BLOCKS_A; i += 256)
        ln[i] = cnt[(size_t)b * BLOCKS_A + i];
    __syncthreads();

    // regions: entries j<min(ln[r],CAP) of cell (r,b); overflow went to spill.
    for (int t = threadIdx.x; t < BLOCKS_A * CAP; t += 256) {
        int r = t >> 6, j = t & (CAP - 1);
        if ((uint32_t)j < ln[r]) {
            uint16_t k = regions[(((size_t)r * NB + b) << 6) + j];
            atomicAdd(&hist[k], 1u);
        }
    }
    int sn = min(*spillCur, SPILLCAP);
    for (int i = threadIdx.x; i < sn; i += 256) {
        int c = (int)spill[i];
        if ((c >> BIN_SHIFT) == b) atomicAdd(&hist[c & (BIN_RANGE - 1)], 1u);
    }
    __syncthreads();

    int base = b << BIN_SHIFT;
    int lim = min(BIN_RANGE, nc - base);
    int lo = 0x7fffffff;
    for (int i = threadIdx.x; i < lim; i += 256) lo = min(lo, (int)hist[i]);
    for (int off = 32; off > 0; off >>= 1) lo = min(lo, __shfl_down(lo, off));
    if ((threadIdx.x & 63) == 0) atomicMin(minslot, lo);
}

__global__ void fin_k(const int* __restrict__ minslot, float* __restrict__ out) {
    out[0] = (float)(*minslot);
}

// ---------------- fallback path (round-2 kernel, known-good) ----------------
static constexpr size_t FB_COUNTS = 0;
static constexpr size_t FB_XB     = 8000000;
static constexpr size_t FB_MIN    = 10000000;

__global__ __launch_bounds__(256) void fb_init_k(uint32_t* __restrict__ counts,
                                                 uint8_t* __restrict__ xb,
                                                 const float* __restrict__ xv,
                                                 int* __restrict__ minslot) {
    int stride = gridDim.x * blockDim.x;
    int i0 = blockIdx.x * blockDim.x + threadIdx.x;
    for (int i = i0; i < NC; i += stride) counts[i] = 0u;
    for (int i = i0; i < NV; i += stride)
        xb[i] = (uint8_t)(int)floorf(xv[i] / 0.50001f);
    if (i0 == 0) *minslot = 0x7fffffff;
}

template<int POS>
__global__ __launch_bounds__(256) void fb_edge_k(const int* __restrict__ adj,
                                                 const uint8_t* __restrict__ xb,
                                                 uint32_t* __restrict__ counts,
                                                 int ne) {
    int stride = gridDim.x * blockDim.x;
    int i0 = blockIdx.x * blockDim.x + threadIdx.x;
    for (int e = i0; e < ne; e += stride) {
        int c = adj[e];
        int v = adj[ne + e];
        int b = (int)xb[v];
        bool sat = POS ? (b != 0) : (b == 0);
        if (sat) atomicAdd(&counts[c], 1u);
    }
}

__global__ __launch_bounds__(256) void fb_min_k(const uint32_t* __restrict__ counts,
                                                int* __restrict__ minslot) {
    int stride = gridDim.x * blockDim.x;
    int i0 = blockIdx.x * blockDim.x + threadIdx.x;
    int lo = 0x7fffffff;
    for (int i = i0; i < NC; i += stride) lo = min(lo, (int)counts[i]);
    for (int off = 32; off > 0; off >>= 1) lo = min(lo, __shfl_down(lo, off));
    if ((threadIdx.x & 63) == 0) atomicMin(minslot, lo);
}

extern "C" void kernel_launch(void* const* d_in, const int* in_sizes, int n_in,
                              void* d_out, int out_size, void* d_ws, size_t ws_size,
                              hipStream_t stream) {
    const float* xv    = (const float*)d_in[0];
    const int* adj_pos = (const int*)d_in[1];   // int32 per harness contract
    const int* adj_neg = (const int*)d_in[2];
    float* out = (float*)d_out;

    const int ne = in_sizes[1] / 2;   // edges per polarity (rows: [clause, var])
    char* ws = (char*)d_ws;
    dim3 blk(256);

    // CAP sized for ne ~ 8M over BLOCKS_A blocks; larger ne would overflow into
    // the (bounded) spill list too often -> use the atomic fallback instead.
    bool use_fast = (ws_size >= WS_NEED) && (ne <= 9000000);

    if (use_fast) {
        uint16_t* regions = (uint16_t*)(ws + WS_REG);
        uint32_t* cnt     = (uint32_t*)(ws + WS_CNT);
        uint8_t*  xb      = (uint8_t*) (ws + WS_XB);
        uint32_t* spill   = (uint32_t*)(ws + WS_SPILL);
        int*      ctrl    = (int*)     (ws + WS_CTRL);
        int* spillCur = ctrl;
        int* minslot  = ctrl + 1;

        int total = 2 * ne;
        int per_block = (total + BLOCKS_A - 1) / BLOCKS_A;

        init_k<<<2048, blk, 0, stream>>>(xv, xb, spillCur, minslot, in_sizes[0]);
        passA_k<<<BLOCKS_A, blk, 0, stream>>>(adj_pos, adj_neg, xb, regions, cnt,
                                              spill, spillCur, ne, per_block);
        passB_k<<<NB, blk, 0, stream>>>(regions, cnt, spill, spillCur, minslot, NC);
        fin_k<<<1, 1, 0, stream>>>(minslot, out);
    } else {
        uint32_t* counts = (uint32_t*)(ws + FB_COUNTS);
        uint8_t*  xb     = (uint8_t*) (ws + FB_XB);
        int*      mins   = (int*)     (ws + FB_MIN);
        fb_init_k<<<2048, blk, 0, stream>>>(counts, xb, xv, mins);
        fb_edge_k<1><<<2048, blk, 0, stream>>>(adj_pos, xb, counts, ne);
        fb_edge_k<0><<<2048, blk, 0, stream>>>(adj_neg, xb, counts, ne);
        fb_min_k<<<2048, blk, 0, stream>>>(counts, mins);
        fin_k<<<1, 1, 0, stream>>>(mins, out);
    }
}